// Round 3
// baseline (155.378 us; speedup 1.0000x reference)
//
#include <hip/hip_runtime.h>
#include <math.h>

#define NHEAD 8
#define DIM   32
#define TOPK  8
#define TEMP  0.17677669529663687f   // 1/sqrt(32)
#define BATCH 4

// Butterfly argmax over 32 lanes, tie-break: lowest index (matches jax.lax.top_k)
__device__ __forceinline__ void argmax32(float& v, int& i) {
#pragma unroll
  for (int off = 16; off >= 1; off >>= 1) {
    float ov = __shfl_xor(v, off, 32);
    int   oi = __shfl_xor(i, off, 32);
    if (ov > v || (ov == v && oi < i)) { v = ov; i = oi; }
  }
}

// ---------------- Transpose [B, 256, S] -> [B, S, 256] for Q,K,V ----------
template <int S>
__global__ __launch_bounds__(256) void transpose_qkv(
    const float* __restrict__ Q, const float* __restrict__ K, const float* __restrict__ V,
    float* __restrict__ Qt, float* __restrict__ Kt, float* __restrict__ Vt)
{
  __shared__ float tile[32][33];
  const int z = blockIdx.z;           // z = tensor*B + b
  const int b = z & (BATCH - 1);
  const int tsel = z >> 2;
  const float* in = tsel == 0 ? Q : tsel == 1 ? K : V;
  float* out      = tsel == 0 ? Qt : tsel == 1 ? Kt : Vt;
  const int s0 = blockIdx.x * 32;
  const int c0 = blockIdx.y * 32;
  const int tx = threadIdx.x & 31;
  const int ty = threadIdx.x >> 5;    // 0..7
  const size_t ibase = ((size_t)b * 256 + c0) * S + s0;
#pragma unroll
  for (int i = ty; i < 32; i += 8)
    tile[i][tx] = in[ibase + (size_t)i * S + tx];
  __syncthreads();
  const size_t obase = ((size_t)b * S + s0) * 256 + c0;
#pragma unroll
  for (int i = ty; i < 32; i += 8)
    out[obase + (size_t)i * 256 + tx] = tile[tx][i];
}

// ---------------- Level 0 (fast): token-major Q/V, 4 queries per block -----
// grid: B*64 blocks, 256 threads = 8 heads x 32 lanes; lane owns s = lane*8+j
__global__ __launch_bounds__(256) void l0_tm_kernel(
    const float* __restrict__ Qt, const float* __restrict__ K, const float* __restrict__ Vt,
    float* __restrict__ msg0, int* __restrict__ tki0, float* __restrict__ tkp0)
{
  const int b   = blockIdx.x >> 6;
  const int lq0 = (blockIdx.x & 63) * 4;
  const int t = threadIdx.x;
  const int h = t >> 5, lane = t & 31;

  __shared__ float q_s[NHEAD][4][DIM];
  __shared__ float probs[NHEAD][4][256];   // slot j*32+lane holds s = lane*8+j

  const size_t tb = (size_t)b * 256 * 256;               // token-major [b, s, c]
  const size_t cb = ((size_t)(b * 256 + h * 32)) * 256;  // channel-major [b, c, s]

#pragma unroll
  for (int q = 0; q < 4; ++q)
    q_s[h][q][lane] = Qt[tb + (size_t)(lq0 + q) * 256 + h * 32 + lane];
  // all LDS here is per-head within one half-wave: no barriers needed

  float sc[4][8];
#pragma unroll
  for (int q = 0; q < 4; ++q)
#pragma unroll
    for (int j = 0; j < 8; ++j) sc[q][j] = 0.f;

  const float* kbase = K + cb + lane * 8;
  for (int d = 0; d < 32; ++d) {
    const float4 ka = *(const float4*)(kbase + (size_t)d * 256);
    const float4 kb = *(const float4*)(kbase + (size_t)d * 256 + 4);
    const float kv[8] = {ka.x, ka.y, ka.z, ka.w, kb.x, kb.y, kb.z, kb.w};
    float qd[4];
#pragma unroll
    for (int q = 0; q < 4; ++q) qd[q] = q_s[h][q][d];
#pragma unroll
    for (int q = 0; q < 4; ++q)
#pragma unroll
      for (int j = 0; j < 8; ++j) sc[q][j] += qd[q] * kv[j];
  }
#pragma unroll
  for (int q = 0; q < 4; ++q)
#pragma unroll
    for (int j = 0; j < 8; ++j) sc[q][j] *= TEMP;

#pragma unroll
  for (int q = 0; q < 4; ++q) {
    // softmax over all 256
    float mx = sc[q][0];
#pragma unroll
    for (int j = 1; j < 8; ++j) mx = fmaxf(mx, sc[q][j]);
#pragma unroll
    for (int off = 16; off >= 1; off >>= 1) mx = fmaxf(mx, __shfl_xor(mx, off, 32));
    float ev[8]; float ssum = 0.f;
#pragma unroll
    for (int j = 0; j < 8; ++j) { ev[j] = expf(sc[q][j] - mx); ssum += ev[j]; }
#pragma unroll
    for (int off = 16; off >= 1; off >>= 1) ssum += __shfl_xor(ssum, off, 32);
    const float inv = 1.f / ssum;

    // top-8 on scaled scores (monotone with probs); global id gi = lane*8+j
    int msk = 0;
#pragma unroll
    for (int k = 0; k < TOPK; ++k) {
      float bv = -INFINITY; int bi = 1 << 30;
#pragma unroll
      for (int j = 0; j < 8; ++j) {
        if (!((msk >> j) & 1)) {
          const int gi = lane * 8 + j;
          if (sc[q][j] > bv || (sc[q][j] == bv && gi < bi)) { bv = sc[q][j]; bi = gi; }
        }
      }
      argmax32(bv, bi);
      if ((bi >> 3) == lane) msk |= 1 << (bi & 7);
      if (lane == k) {
        const int o = ((b * 256 + lq0 + q) * TOPK + k) * NHEAD + h;
        tki0[o] = bi;
        tkp0[o] = expf(bv - mx) * inv;
      }
    }

    // masked probabilities, bank-conflict-free permuted store
#pragma unroll
    for (int j = 0; j < 8; ++j)
      probs[h][q][j * 32 + lane] = ((msk >> j) & 1) ? 0.f : ev[j] * inv;
  }

  // message: lane = d, natural s order (matches prior rounds' numerics)
  float acc[4] = {0.f, 0.f, 0.f, 0.f};
  const float* vrow = Vt + tb + h * 32 + lane;
#pragma unroll 8
  for (int s = 0; s < 256; ++s) {
    const float vval = vrow[(size_t)s * 256];
    const int e = ((s & 7) << 5) | (s >> 3);
#pragma unroll
    for (int q = 0; q < 4; ++q) acc[q] += probs[h][q][e] * vval;
  }
#pragma unroll
  for (int q = 0; q < 4; ++q)
    msg0[((size_t)(b * 256 + lq0 + q) * NHEAD + h) * DIM + lane] = acc[q];
}

// ---------------- Level 0 (fallback): channel-major ------------------------
__global__ __launch_bounds__(256) void l0_cm_kernel(
    const float* __restrict__ Q, const float* __restrict__ K, const float* __restrict__ V,
    float* __restrict__ msg0, int* __restrict__ tki0, float* __restrict__ tkp0)
{
  const int b = blockIdx.x >> 8;
  const int l = blockIdx.x & 255;
  const int t = threadIdx.x;
  const int h = t >> 5, lane = t & 31;

  __shared__ float q_s[NHEAD][DIM];
  __shared__ float probs[NHEAD][256];
  __shared__ int   tk_i[NHEAD][TOPK];
  __shared__ float tk_p[NHEAD][TOPK];

  const size_t cb = ((size_t)(b * 256 + h * 32)) * 256;
  q_s[h][lane] = Q[cb + (size_t)lane * 256 + l];

  float sc[8];
#pragma unroll
  for (int j = 0; j < 8; ++j) sc[j] = 0.f;
  for (int d = 0; d < 32; ++d) {
    const float qd = q_s[h][d];
    const float* kr = K + cb + (size_t)d * 256;
#pragma unroll
    for (int j = 0; j < 8; ++j) sc[j] += qd * kr[j * 32 + lane];
  }
#pragma unroll
  for (int j = 0; j < 8; ++j) sc[j] *= TEMP;

  float mx = sc[0];
#pragma unroll
  for (int j = 1; j < 8; ++j) mx = fmaxf(mx, sc[j]);
#pragma unroll
  for (int off = 16; off >= 1; off >>= 1) mx = fmaxf(mx, __shfl_xor(mx, off, 32));
  float ev[8]; float ssum = 0.f;
#pragma unroll
  for (int j = 0; j < 8; ++j) { ev[j] = expf(sc[j] - mx); ssum += ev[j]; }
#pragma unroll
  for (int off = 16; off >= 1; off >>= 1) ssum += __shfl_xor(ssum, off, 32);
  const float inv = 1.f / ssum;

  int msk = 0;
#pragma unroll
  for (int k = 0; k < TOPK; ++k) {
    float bv = -INFINITY; int bi = 1 << 30;
#pragma unroll
    for (int j = 0; j < 8; ++j) {
      if (!((msk >> j) & 1)) {
        int gi = j * 32 + lane;
        if (sc[j] > bv || (sc[j] == bv && gi < bi)) { bv = sc[j]; bi = gi; }
      }
    }
    argmax32(bv, bi);
    if ((bi & 31) == lane) msk |= 1 << (bi >> 5);
    if (lane == 0) { tk_i[h][k] = bi; tk_p[h][k] = expf(bv - mx) * inv; }
  }

#pragma unroll
  for (int j = 0; j < 8; ++j)
    probs[h][j * 32 + lane] = ((msk >> j) & 1) ? 0.f : ev[j] * inv;
  __syncthreads();

  float acc = 0.f;
  const float* vr = V + cb + (size_t)lane * 256;
  for (int s = 0; s < 256; ++s) acc += probs[h][s] * vr[s];

  msg0[((size_t)(b * 256 + l) * NHEAD + h) * DIM + lane] = acc;
  if (lane < TOPK) {
    const int o = ((b * 256 + l) * TOPK + lane) * NHEAD + h;
    tki0[o] = tk_i[h][lane];
    tkp0[o] = tk_p[h][lane];
  }
}

// ---------------- Token-major refinement (fast path) -----------------------
template <int W, bool HAS_TOPK>
__global__ __launch_bounds__(256) void refine_tm_kernel(
    const float* __restrict__ Qt, const float* __restrict__ Kt, const float* __restrict__ Vt,
    const float* __restrict__ msgp, const int* __restrict__ tkip, const float* __restrict__ tkpp,
    float* __restrict__ msgo, int* __restrict__ tkio, float* __restrict__ tkpo)
{
  constexpr int S  = W * W;
  constexpr int HW = W / 2;
  constexpr int Lp = HW * HW;
  const int b = blockIdx.x / Lp;
  const int l = blockIdx.x % Lp;
  const int gr = l / HW, gc = l % HW;
  const int t = threadIdx.x;
  const int h = t >> 5, lane = t & 31;

  __shared__ float q_s[NHEAD][4][DIM];
  __shared__ int   cidx_s[NHEAD][32];
  __shared__ float w_s[NHEAD][32];

  const int k0 = lane >> 2, f = lane & 3;
  const int pofs = ((b * Lp + l) * TOPK + k0) * NHEAD + h;
  const int ti = tkip[pofs];
  const float csc = tkpp[pofs];
  const int cidx = ((ti / HW) * 2 + (f >> 1)) * W + ((ti % HW) * 2 + (f & 1));
  cidx_s[h][lane] = cidx;
  // all shared arrays per-head within one half-wave -> no barriers

#pragma unroll
  for (int wq = 0; wq < 4; ++wq) {
    const int rr = 2 * gr + (wq >> 1), cc = 2 * gc + (wq & 1);
    q_s[h][wq][lane] = Qt[((size_t)b * S + rr * W + cc) * 256 + h * DIM + lane];
  }

  float kv[DIM];
  {
    const float4* kp = (const float4*)(Kt + ((size_t)b * S + cidx) * 256 + h * DIM);
#pragma unroll
    for (int j = 0; j < 8; ++j) {
      const float4 v4 = kp[j];
      kv[4 * j] = v4.x; kv[4 * j + 1] = v4.y; kv[4 * j + 2] = v4.z; kv[4 * j + 3] = v4.w;
    }
  }

  float vv[32];
#pragma unroll
  for (int e = 0; e < 32; ++e)
    vv[e] = Vt[((size_t)b * S + cidx_s[h][e]) * 256 + h * DIM + lane];

  const float mprev = msgp[((size_t)(b * Lp + l) * NHEAD + h) * DIM + lane];

#pragma unroll
  for (int wq = 0; wq < 4; ++wq) {
    float qk = 0.f;
#pragma unroll
    for (int d = 0; d < DIM; ++d) qk += q_s[h][wq][d] * kv[d];
    const float sval = TEMP * qk;

    float m1 = fmaxf(sval, __shfl_xor(sval, 1, 4));
    float m2 = fmaxf(m1, __shfl_xor(m1, 2, 4));
    float ex = expf(sval - m2);
    float s1 = ex + __shfl_xor(ex, 1, 4);
    float s2 = s1 + __shfl_xor(s1, 2, 4);
    const float A = (ex / s2) * csc;

    float Am = A;
    int   my_e = 0; float my_v = 0.f;
    if constexpr (HAS_TOPK) {
      bool mymask = false;
#pragma unroll
      for (int k = 0; k < TOPK; ++k) {
        float bv = mymask ? -INFINITY : A;
        int bi = lane;
        argmax32(bv, bi);
        if (bi == lane) mymask = true;
        if (lane == k) { my_e = bi; my_v = bv; }
      }
      if (mymask) Am = 0.f;
    }

    w_s[h][lane] = Am;

    float acc = 0.f;
#pragma unroll
    for (int e = 0; e < 32; ++e) acc += w_s[h][e] * vv[e];
    const float outv = mprev + acc;

    const int rr = 2 * gr + (wq >> 1), cc = 2 * gc + (wq & 1);
    const int tok = rr * W + cc;
    msgo[((size_t)(b * S + tok) * NHEAD + h) * DIM + lane] = outv;
    if constexpr (HAS_TOPK) {
      if (lane < TOPK) {
        const int o = ((b * S + tok) * TOPK + lane) * NHEAD + h;
        tkio[o] = cidx_s[h][my_e];
        tkpo[o] = my_v;
      }
    }
  }
}

// ---------------- Channel-major refinement (fallback) ----------------------
template <int W, bool HAS_TOPK>
__global__ __launch_bounds__(256) void refine_cm_kernel(
    const float* __restrict__ Q, const float* __restrict__ K, const float* __restrict__ V,
    const float* __restrict__ msgp, const int* __restrict__ tkip, const float* __restrict__ tkpp,
    float* __restrict__ msgo, int* __restrict__ tkio, float* __restrict__ tkpo)
{
  constexpr int S  = W * W;
  constexpr int HW = W / 2;
  constexpr int Lp = HW * HW;
  const int b = blockIdx.x / Lp;
  const int l = blockIdx.x % Lp;
  const int gr = l / HW, gc = l % HW;
  const int t = threadIdx.x;
  const int h = t >> 5, lane = t & 31;

  __shared__ float q_s[4][NHEAD][DIM];
  __shared__ int   cidx_s[NHEAD][32];
  __shared__ float w_s[NHEAD][32];

  const size_t cbase = ((size_t)(b * 256 + h * 32)) * S;

#pragma unroll
  for (int wq = 0; wq < 4; ++wq) {
    const int rr = 2 * gr + (wq >> 1), cc = 2 * gc + (wq & 1);
    q_s[wq][h][lane] = Q[cbase + (size_t)lane * S + rr * W + cc];
  }

  const int k0 = lane >> 2, f = lane & 3;
  const int pofs = ((b * Lp + l) * TOPK + k0) * NHEAD + h;
  const int ti = tkip[pofs];
  const float csc = tkpp[pofs];
  cidx_s[h][lane] = ((ti / HW) * 2 + (f >> 1)) * W + ((ti % HW) * 2 + (f & 1));
  const int cidx = cidx_s[h][lane];

  float kv[DIM];
#pragma unroll
  for (int d = 0; d < DIM; ++d) kv[d] = K[cbase + (size_t)d * S + cidx];

  const float mprev = msgp[((size_t)(b * Lp + l) * NHEAD + h) * DIM + lane];

  for (int wq = 0; wq < 4; ++wq) {
    float qk = 0.f;
#pragma unroll
    for (int d = 0; d < DIM; ++d) qk += q_s[wq][h][d] * kv[d];
    const float v = TEMP * qk;

    float m1 = fmaxf(v, __shfl_xor(v, 1, 4));
    float m2 = fmaxf(m1, __shfl_xor(m1, 2, 4));
    float ex = expf(v - m2);
    float s1 = ex + __shfl_xor(ex, 1, 4);
    float s2 = s1 + __shfl_xor(s1, 2, 4);
    const float A = (ex / s2) * csc;

    float Am = A;
    int   my_e = 0; float my_v = 0.f;
    if constexpr (HAS_TOPK) {
      bool mymask = false;
#pragma unroll
      for (int k = 0; k < TOPK; ++k) {
        float bv = mymask ? -INFINITY : A;
        int bi = lane;
        argmax32(bv, bi);
        if (bi == lane) mymask = true;
        if (lane == k) { my_e = bi; my_v = bv; }
      }
      if (mymask) Am = 0.f;
    }

    w_s[h][lane] = Am;

    float acc = 0.f;
    const float* vcol = V + cbase + (size_t)lane * S;
#pragma unroll
    for (int e = 0; e < 32; ++e) acc += w_s[h][e] * vcol[cidx_s[h][e]];
    const float outv = mprev + acc;

    const int rr = 2 * gr + (wq >> 1), cc = 2 * gc + (wq & 1);
    const int tok = rr * W + cc;
    msgo[((size_t)(b * S + tok) * NHEAD + h) * DIM + lane] = outv;
    if constexpr (HAS_TOPK) {
      if (lane < TOPK) {
        const int o = ((b * S + tok) * TOPK + lane) * NHEAD + h;
        tkio[o] = cidx_s[h][my_e];
        tkpo[o] = my_v;
      }
    }
  }
}

extern "C" void kernel_launch(void* const* d_in, const int* in_sizes, int n_in,
                              void* d_out, int out_size, void* d_ws, size_t ws_size,
                              hipStream_t stream)
{
  const float* Q0 = (const float*)d_in[0];  // 64x64 (fine)
  const float* Q1 = (const float*)d_in[1];  // 32x32
  const float* Q2 = (const float*)d_in[2];  // 16x16 (coarse)
  const float* K0 = (const float*)d_in[3];
  const float* K1 = (const float*)d_in[4];
  const float* K2 = (const float*)d_in[5];
  const float* V0 = (const float*)d_in[6];
  const float* V1 = (const float*)d_in[7];
  const float* V2 = (const float*)d_in[8];
  float* out = (float*)d_out;

  const size_t N_MSG0 = (size_t)BATCH * 256 * NHEAD * DIM;
  const size_t N_TK0  = (size_t)BATCH * 256 * TOPK * NHEAD;
  const size_t N_MSG1 = (size_t)BATCH * 1024 * NHEAD * DIM;
  const size_t N_TK1  = (size_t)BATCH * 1024 * TOPK * NHEAD;
  const size_t N_T2   = (size_t)BATCH * 256 * 256;
  const size_t N_T1   = (size_t)BATCH * 1024 * 256;
  const size_t N_T0   = (size_t)BATCH * 4096 * 256;

  float* p = (float*)d_ws;
  float* msg0 = p;            p += N_MSG0;
  int*   tki0 = (int*)p;      p += N_TK0;
  float* tkp0 = p;            p += N_TK0;
  float* msg1 = p;            p += N_MSG1;
  int*   tki1 = (int*)p;      p += N_TK1;
  float* tkp1 = p;            p += N_TK1;
  float* Qt2  = p;            p += N_T2;
  float* Kt2  = p;            p += N_T2;
  float* Vt2  = p;            p += N_T2;
  float* Qt1  = p;            p += N_T1;
  float* Kt1  = p;            p += N_T1;
  float* Vt1  = p;            p += N_T1;
  float* Qt0  = p;            p += N_T0;
  float* Kt0  = p;            p += N_T0;
  float* Vt0  = p;            p += N_T0;
  const size_t need_bytes = (size_t)(p - (float*)d_ws) * sizeof(float);

  if (ws_size >= need_bytes) {
    hipLaunchKernelGGL((transpose_qkv<256>), dim3(8, 8, 3 * BATCH), dim3(256), 0, stream,
                       Q2, K2, V2, Qt2, Kt2, Vt2);
    hipLaunchKernelGGL(l0_tm_kernel, dim3(BATCH * 64), dim3(256), 0, stream,
                       Qt2, K2, Vt2, msg0, tki0, tkp0);
    hipLaunchKernelGGL((transpose_qkv<1024>), dim3(32, 8, 3 * BATCH), dim3(256), 0, stream,
                       Q1, K1, V1, Qt1, Kt1, Vt1);
    hipLaunchKernelGGL((transpose_qkv<4096>), dim3(128, 8, 3 * BATCH), dim3(256), 0, stream,
                       Q0, K0, V0, Qt0, Kt0, Vt0);
    hipLaunchKernelGGL((refine_tm_kernel<32, true>), dim3(BATCH * 256), dim3(256), 0, stream,
                       Qt1, Kt1, Vt1, msg0, tki0, tkp0, msg1, tki1, tkp1);
    hipLaunchKernelGGL((refine_tm_kernel<64, false>), dim3(BATCH * 1024), dim3(256), 0, stream,
                       Qt0, Kt0, Vt0, msg1, tki1, tkp1, out, nullptr, nullptr);
  } else {
    hipLaunchKernelGGL(l0_cm_kernel, dim3(BATCH * 256), dim3(256), 0, stream,
                       Q2, K2, V2, msg0, tki0, tkp0);
    hipLaunchKernelGGL((refine_cm_kernel<32, true>), dim3(BATCH * 256), dim3(256), 0, stream,
                       Q1, K1, V1, msg0, tki0, tkp0, msg1, tki1, tkp1);
    hipLaunchKernelGGL((refine_cm_kernel<64, false>), dim3(BATCH * 1024), dim3(256), 0, stream,
                       Q0, K0, V0, msg1, tki1, tkp1, out, nullptr, nullptr);
  }
}

// Round 4
// 131.037 us; speedup vs baseline: 1.1858x; 1.1858x over previous
//
#include <hip/hip_runtime.h>
#include <math.h>

#define NHEAD 8
#define DIM   32
#define TOPK  8
#define TEMP  0.17677669529663687f   // 1/sqrt(32)
#define BATCH 4

// Butterfly argmax over 32 lanes, tie-break: lowest index (matches jax.lax.top_k)
__device__ __forceinline__ void argmax32(float& v, int& i) {
#pragma unroll
  for (int off = 16; off >= 1; off >>= 1) {
    float ov = __shfl_xor(v, off, 32);
    int   oi = __shfl_xor(i, off, 32);
    if (ov > v || (ov == v && oi < i)) { v = ov; i = oi; }
  }
}

// ---------------- Fused transpose: all levels/tensors, one launch ----------
// [B, 256, S] -> [B, S, 256]. Flat grid of 32x32 tiles:
//  job V2 (S=256): 256 tiles; jobs Q1,K1,V1 (S=1024): 3072; Q0,K0,V0: 12288.
__global__ __launch_bounds__(256) void transpose_all(
    const float* __restrict__ V2, float* __restrict__ Vt2,
    const float* __restrict__ Q1, const float* __restrict__ K1, const float* __restrict__ V1,
    float* __restrict__ Qt1, float* __restrict__ Kt1, float* __restrict__ Vt1,
    const float* __restrict__ Q0, const float* __restrict__ K0, const float* __restrict__ V0,
    float* __restrict__ Qt0, float* __restrict__ Kt0, float* __restrict__ Vt0)
{
  __shared__ float tile[32][36];
  int id = blockIdx.x;
  const float* in; float* out; int S, b, t;
  if (id < 256) {                       // level2 V only
    S = 256; in = V2; out = Vt2;
    b = id >> 6; t = id & 63;
  } else if (id < 256 + 3072) {         // level1 Q,K,V
    id -= 256; S = 1024;
    const int tsel = id >> 10;          // /1024
    in  = tsel == 0 ? Q1 : tsel == 1 ? K1 : V1;
    out = tsel == 0 ? Qt1 : tsel == 1 ? Kt1 : Vt1;
    b = (id >> 8) & 3; t = id & 255;
  } else {                              // level0 Q,K,V
    id -= 256 + 3072; S = 4096;
    const int tsel = id >> 12;          // /4096
    in  = tsel == 0 ? Q0 : tsel == 1 ? K0 : V0;
    out = tsel == 0 ? Qt0 : tsel == 1 ? Kt0 : Vt0;
    b = (id >> 10) & 3; t = id & 1023;
  }
  const int ntx = S >> 5;               // s-tiles per row
  const int sx = t / 8, cy = t % 8;     // t < ntx*8; sx < ntx
  (void)ntx;
  const int s0 = sx * 32, c0 = cy * 32;
  const int tid = threadIdx.x;
  const int i = tid >> 3, c4 = tid & 7;

  // load: row i (channel), 4 s-elems
  const float4 v4 = *(const float4*)(in + ((size_t)b * 256 + c0 + i) * S + s0 + c4 * 4);
  *(float4*)&tile[i][c4 * 4] = v4;
  __syncthreads();
  // store: row i (token s), 4 c-elems
  float4 w;
  w.x = tile[c4 * 4 + 0][i];
  w.y = tile[c4 * 4 + 1][i];
  w.z = tile[c4 * 4 + 2][i];
  w.w = tile[c4 * 4 + 3][i];
  *(float4*)(out + ((size_t)b * S + s0 + i) * 256 + c0 + c4 * 4) = w;
}

// ---------------- Level 0 v4: 1 query/block, float4 K, token-major V -------
// grid: B*256 blocks, 256 threads = 8 heads x 32 lanes; lane owns s=lane*8+j
__global__ __launch_bounds__(256) void l0_kernel_v4(
    const float* __restrict__ Q, const float* __restrict__ K, const float* __restrict__ Vt,
    float* __restrict__ msg0, int* __restrict__ tki0, float* __restrict__ tkp0)
{
  const int b = blockIdx.x >> 8;
  const int l = blockIdx.x & 255;
  const int t = threadIdx.x;
  const int h = t >> 5, lane = t & 31;

  __shared__ float q_s[NHEAD][DIM];
  __shared__ float probs[NHEAD][256];   // slot j*32+lane holds s = lane*8+j

  const size_t cb = ((size_t)(b * 256 + h * 32)) * 256;  // channel-major [b,c,s]
  const size_t tb = (size_t)b * 256 * 256;               // token-major [b,s,c]

  q_s[h][lane] = Q[cb + (size_t)lane * 256 + l];
  // all LDS per-head within one half-wave: no barriers needed

  float sc[8];
#pragma unroll
  for (int j = 0; j < 8; ++j) sc[j] = 0.f;
  const float* kbase = K + cb + lane * 8;
  for (int d = 0; d < 32; ++d) {
    const float4 ka = *(const float4*)(kbase + (size_t)d * 256);
    const float4 kb = *(const float4*)(kbase + (size_t)d * 256 + 4);
    const float qd = q_s[h][d];
    sc[0] += qd * ka.x; sc[1] += qd * ka.y; sc[2] += qd * ka.z; sc[3] += qd * ka.w;
    sc[4] += qd * kb.x; sc[5] += qd * kb.y; sc[6] += qd * kb.z; sc[7] += qd * kb.w;
  }
#pragma unroll
  for (int j = 0; j < 8; ++j) sc[j] *= TEMP;

  // softmax over all 256
  float mx = sc[0];
#pragma unroll
  for (int j = 1; j < 8; ++j) mx = fmaxf(mx, sc[j]);
#pragma unroll
  for (int off = 16; off >= 1; off >>= 1) mx = fmaxf(mx, __shfl_xor(mx, off, 32));
  float ev[8]; float ssum = 0.f;
#pragma unroll
  for (int j = 0; j < 8; ++j) { ev[j] = expf(sc[j] - mx); ssum += ev[j]; }
#pragma unroll
  for (int off = 16; off >= 1; off >>= 1) ssum += __shfl_xor(ssum, off, 32);
  const float inv = 1.f / ssum;

  // top-8 on scaled scores; global id gi = lane*8+j (ascending = tie-break order)
  int msk = 0;
#pragma unroll
  for (int k = 0; k < TOPK; ++k) {
    float bv = -INFINITY; int bi = 1 << 30;
#pragma unroll
    for (int j = 0; j < 8; ++j) {
      if (!((msk >> j) & 1)) {
        const int gi = lane * 8 + j;
        if (sc[j] > bv || (sc[j] == bv && gi < bi)) { bv = sc[j]; bi = gi; }
      }
    }
    argmax32(bv, bi);
    if ((bi >> 3) == lane) msk |= 1 << (bi & 7);
    if (lane == k) {
      const int o = ((b * 256 + l) * TOPK + k) * NHEAD + h;
      tki0[o] = bi;
      tkp0[o] = expf(bv - mx) * inv;
    }
  }

  // masked probabilities (top-k zeroed == sum-then-subtract up to fp rounding)
#pragma unroll
  for (int j = 0; j < 8; ++j)
    probs[h][j * 32 + lane] = ((msk >> j) & 1) ? 0.f : ev[j] * inv;

  // message: lane = d, natural s order; Vt coalesced (256 threads -> 1KB/instr)
  float acc = 0.f;
  const float* vrow = Vt + tb + h * 32 + lane;
#pragma unroll 8
  for (int s = 0; s < 256; ++s)
    acc += probs[h][((s & 7) << 5) | (s >> 3)] * vrow[(size_t)s * 256];

  msg0[((size_t)(b * 256 + l) * NHEAD + h) * DIM + lane] = acc;
}

// ---------------- Level 0 (fallback): channel-major ------------------------
__global__ __launch_bounds__(256) void l0_cm_kernel(
    const float* __restrict__ Q, const float* __restrict__ K, const float* __restrict__ V,
    float* __restrict__ msg0, int* __restrict__ tki0, float* __restrict__ tkp0)
{
  const int b = blockIdx.x >> 8;
  const int l = blockIdx.x & 255;
  const int t = threadIdx.x;
  const int h = t >> 5, lane = t & 31;

  __shared__ float q_s[NHEAD][DIM];
  __shared__ float probs[NHEAD][256];

  const size_t cb = ((size_t)(b * 256 + h * 32)) * 256;
  q_s[h][lane] = Q[cb + (size_t)lane * 256 + l];

  float sc[8];
#pragma unroll
  for (int j = 0; j < 8; ++j) sc[j] = 0.f;
  for (int d = 0; d < 32; ++d) {
    const float qd = q_s[h][d];
    const float* kr = K + cb + (size_t)d * 256;
#pragma unroll
    for (int j = 0; j < 8; ++j) sc[j] += qd * kr[j * 32 + lane];
  }
#pragma unroll
  for (int j = 0; j < 8; ++j) sc[j] *= TEMP;

  float mx = sc[0];
#pragma unroll
  for (int j = 1; j < 8; ++j) mx = fmaxf(mx, sc[j]);
#pragma unroll
  for (int off = 16; off >= 1; off >>= 1) mx = fmaxf(mx, __shfl_xor(mx, off, 32));
  float ev[8]; float ssum = 0.f;
#pragma unroll
  for (int j = 0; j < 8; ++j) { ev[j] = expf(sc[j] - mx); ssum += ev[j]; }
#pragma unroll
  for (int off = 16; off >= 1; off >>= 1) ssum += __shfl_xor(ssum, off, 32);
  const float inv = 1.f / ssum;

  int msk = 0;
#pragma unroll
  for (int k = 0; k < TOPK; ++k) {
    float bv = -INFINITY; int bi = 1 << 30;
#pragma unroll
    for (int j = 0; j < 8; ++j) {
      if (!((msk >> j) & 1)) {
        int gi = j * 32 + lane;
        if (sc[j] > bv || (sc[j] == bv && gi < bi)) { bv = sc[j]; bi = gi; }
      }
    }
    argmax32(bv, bi);
    if ((bi & 31) == lane) msk |= 1 << (bi >> 5);
    if (lane == k) {
      const int o = ((b * 256 + l) * TOPK + k) * NHEAD + h;
      tki0[o] = bi;
      tkp0[o] = expf(bv - mx) * inv;
    }
  }

#pragma unroll
  for (int j = 0; j < 8; ++j)
    probs[h][j * 32 + lane] = ((msk >> j) & 1) ? 0.f : ev[j] * inv;
  __syncthreads();

  float acc = 0.f;
  const float* vr = V + cb + (size_t)lane * 256;
  for (int s = 0; s < 256; ++s) acc += probs[h][s] * vr[s];

  msg0[((size_t)(b * 256 + l) * NHEAD + h) * DIM + lane] = acc;
}

// ---------------- Token-major refinement (fast path) -----------------------
template <int W, bool HAS_TOPK>
__global__ __launch_bounds__(256) void refine_tm_kernel(
    const float* __restrict__ Qt, const float* __restrict__ Kt, const float* __restrict__ Vt,
    const float* __restrict__ msgp, const int* __restrict__ tkip, const float* __restrict__ tkpp,
    float* __restrict__ msgo, int* __restrict__ tkio, float* __restrict__ tkpo)
{
  constexpr int S  = W * W;
  constexpr int HW = W / 2;
  constexpr int Lp = HW * HW;
  const int b = blockIdx.x / Lp;
  const int l = blockIdx.x % Lp;
  const int gr = l / HW, gc = l % HW;
  const int t = threadIdx.x;
  const int h = t >> 5, lane = t & 31;

  __shared__ float q_s[NHEAD][4][DIM];
  __shared__ int   cidx_s[NHEAD][32];
  __shared__ float w_s[NHEAD][32];

  const int k0 = lane >> 2, f = lane & 3;
  const int pofs = ((b * Lp + l) * TOPK + k0) * NHEAD + h;
  const int ti = tkip[pofs];
  const float csc = tkpp[pofs];
  const int cidx = ((ti / HW) * 2 + (f >> 1)) * W + ((ti % HW) * 2 + (f & 1));
  cidx_s[h][lane] = cidx;
  // all shared arrays per-head within one half-wave -> no barriers

#pragma unroll
  for (int wq = 0; wq < 4; ++wq) {
    const int rr = 2 * gr + (wq >> 1), cc = 2 * gc + (wq & 1);
    q_s[h][wq][lane] = Qt[((size_t)b * S + rr * W + cc) * 256 + h * DIM + lane];
  }

  float kv[DIM];
  {
    const float4* kp = (const float4*)(Kt + ((size_t)b * S + cidx) * 256 + h * DIM);
#pragma unroll
    for (int j = 0; j < 8; ++j) {
      const float4 v4 = kp[j];
      kv[4 * j] = v4.x; kv[4 * j + 1] = v4.y; kv[4 * j + 2] = v4.z; kv[4 * j + 3] = v4.w;
    }
  }

  float vv[32];
#pragma unroll
  for (int e = 0; e < 32; ++e)
    vv[e] = Vt[((size_t)b * S + cidx_s[h][e]) * 256 + h * DIM + lane];

  const float mprev = msgp[((size_t)(b * Lp + l) * NHEAD + h) * DIM + lane];

#pragma unroll
  for (int wq = 0; wq < 4; ++wq) {
    float qk = 0.f;
#pragma unroll
    for (int d = 0; d < DIM; ++d) qk += q_s[h][wq][d] * kv[d];
    const float sval = TEMP * qk;

    float m1 = fmaxf(sval, __shfl_xor(sval, 1, 4));
    float m2 = fmaxf(m1, __shfl_xor(m1, 2, 4));
    float ex = expf(sval - m2);
    float s1 = ex + __shfl_xor(ex, 1, 4);
    float s2 = s1 + __shfl_xor(s1, 2, 4);
    const float A = (ex / s2) * csc;

    float Am = A;
    int   my_e = 0; float my_v = 0.f;
    if constexpr (HAS_TOPK) {
      bool mymask = false;
#pragma unroll
      for (int k = 0; k < TOPK; ++k) {
        float bv = mymask ? -INFINITY : A;
        int bi = lane;
        argmax32(bv, bi);
        if (bi == lane) mymask = true;
        if (lane == k) { my_e = bi; my_v = bv; }
      }
      if (mymask) Am = 0.f;
    }

    w_s[h][lane] = Am;

    float acc = 0.f;
#pragma unroll
    for (int e = 0; e < 32; ++e) acc += w_s[h][e] * vv[e];
    const float outv = mprev + acc;

    const int rr = 2 * gr + (wq >> 1), cc = 2 * gc + (wq & 1);
    const int tok = rr * W + cc;
    msgo[((size_t)(b * S + tok) * NHEAD + h) * DIM + lane] = outv;
    if constexpr (HAS_TOPK) {
      if (lane < TOPK) {
        const int o = ((b * S + tok) * TOPK + lane) * NHEAD + h;
        tkio[o] = cidx_s[h][my_e];
        tkpo[o] = my_v;
      }
    }
  }
}

// ---------------- Channel-major refinement (fallback) ----------------------
template <int W, bool HAS_TOPK>
__global__ __launch_bounds__(256) void refine_cm_kernel(
    const float* __restrict__ Q, const float* __restrict__ K, const float* __restrict__ V,
    const float* __restrict__ msgp, const int* __restrict__ tkip, const float* __restrict__ tkpp,
    float* __restrict__ msgo, int* __restrict__ tkio, float* __restrict__ tkpo)
{
  constexpr int S  = W * W;
  constexpr int HW = W / 2;
  constexpr int Lp = HW * HW;
  const int b = blockIdx.x / Lp;
  const int l = blockIdx.x % Lp;
  const int gr = l / HW, gc = l % HW;
  const int t = threadIdx.x;
  const int h = t >> 5, lane = t & 31;

  __shared__ float q_s[4][NHEAD][DIM];
  __shared__ int   cidx_s[NHEAD][32];
  __shared__ float w_s[NHEAD][32];

  const size_t cbase = ((size_t)(b * 256 + h * 32)) * S;

#pragma unroll
  for (int wq = 0; wq < 4; ++wq) {
    const int rr = 2 * gr + (wq >> 1), cc = 2 * gc + (wq & 1);
    q_s[wq][h][lane] = Q[cbase + (size_t)lane * S + rr * W + cc];
  }

  const int k0 = lane >> 2, f = lane & 3;
  const int pofs = ((b * Lp + l) * TOPK + k0) * NHEAD + h;
  const int ti = tkip[pofs];
  const float csc = tkpp[pofs];
  cidx_s[h][lane] = ((ti / HW) * 2 + (f >> 1)) * W + ((ti % HW) * 2 + (f & 1));
  const int cidx = cidx_s[h][lane];

  float kv[DIM];
#pragma unroll
  for (int d = 0; d < DIM; ++d) kv[d] = K[cbase + (size_t)d * S + cidx];

  const float mprev = msgp[((size_t)(b * Lp + l) * NHEAD + h) * DIM + lane];

  for (int wq = 0; wq < 4; ++wq) {
    float qk = 0.f;
#pragma unroll
    for (int d = 0; d < DIM; ++d) qk += q_s[wq][h][d] * kv[d];
    const float v = TEMP * qk;

    float m1 = fmaxf(v, __shfl_xor(v, 1, 4));
    float m2 = fmaxf(m1, __shfl_xor(m1, 2, 4));
    float ex = expf(v - m2);
    float s1 = ex + __shfl_xor(ex, 1, 4);
    float s2 = s1 + __shfl_xor(s1, 2, 4);
    const float A = (ex / s2) * csc;

    float Am = A;
    int   my_e = 0; float my_v = 0.f;
    if constexpr (HAS_TOPK) {
      bool mymask = false;
#pragma unroll
      for (int k = 0; k < TOPK; ++k) {
        float bv = mymask ? -INFINITY : A;
        int bi = lane;
        argmax32(bv, bi);
        if (bi == lane) mymask = true;
        if (lane == k) { my_e = bi; my_v = bv; }
      }
      if (mymask) Am = 0.f;
    }

    w_s[h][lane] = Am;

    float acc = 0.f;
    const float* vcol = V + cbase + (size_t)lane * S;
#pragma unroll
    for (int e = 0; e < 32; ++e) acc += w_s[h][e] * vcol[cidx_s[h][e]];
    const float outv = mprev + acc;

    const int rr = 2 * gr + (wq >> 1), cc = 2 * gc + (wq & 1);
    const int tok = rr * W + cc;
    msgo[((size_t)(b * S + tok) * NHEAD + h) * DIM + lane] = outv;
    if constexpr (HAS_TOPK) {
      if (lane < TOPK) {
        const int o = ((b * S + tok) * TOPK + lane) * NHEAD + h;
        tkio[o] = cidx_s[h][my_e];
        tkpo[o] = my_v;
      }
    }
  }
}

extern "C" void kernel_launch(void* const* d_in, const int* in_sizes, int n_in,
                              void* d_out, int out_size, void* d_ws, size_t ws_size,
                              hipStream_t stream)
{
  const float* Q0 = (const float*)d_in[0];  // 64x64 (fine)
  const float* Q1 = (const float*)d_in[1];  // 32x32
  const float* Q2 = (const float*)d_in[2];  // 16x16 (coarse)
  const float* K0 = (const float*)d_in[3];
  const float* K1 = (const float*)d_in[4];
  const float* K2 = (const float*)d_in[5];
  const float* V0 = (const float*)d_in[6];
  const float* V1 = (const float*)d_in[7];
  const float* V2 = (const float*)d_in[8];
  float* out = (float*)d_out;

  const size_t N_MSG0 = (size_t)BATCH * 256 * NHEAD * DIM;
  const size_t N_TK0  = (size_t)BATCH * 256 * TOPK * NHEAD;
  const size_t N_MSG1 = (size_t)BATCH * 1024 * NHEAD * DIM;
  const size_t N_TK1  = (size_t)BATCH * 1024 * TOPK * NHEAD;
  const size_t N_T2   = (size_t)BATCH * 256 * 256;
  const size_t N_T1   = (size_t)BATCH * 1024 * 256;
  const size_t N_T0   = (size_t)BATCH * 4096 * 256;

  float* p = (float*)d_ws;
  float* msg0 = p;            p += N_MSG0;
  int*   tki0 = (int*)p;      p += N_TK0;
  float* tkp0 = p;            p += N_TK0;
  float* msg1 = p;            p += N_MSG1;
  int*   tki1 = (int*)p;      p += N_TK1;
  float* tkp1 = p;            p += N_TK1;
  float* Vt2  = p;            p += N_T2;
  float* Qt1  = p;            p += N_T1;
  float* Kt1  = p;            p += N_T1;
  float* Vt1  = p;            p += N_T1;
  float* Qt0  = p;            p += N_T0;
  float* Kt0  = p;            p += N_T0;
  float* Vt0  = p;            p += N_T0;
  const size_t need_bytes = (size_t)(p - (float*)d_ws) * sizeof(float);

  if (ws_size >= need_bytes) {
    hipLaunchKernelGGL(transpose_all, dim3(256 + 3072 + 12288), dim3(256), 0, stream,
                       V2, Vt2, Q1, K1, V1, Qt1, Kt1, Vt1, Q0, K0, V0, Qt0, Kt0, Vt0);
    hipLaunchKernelGGL(l0_kernel_v4, dim3(BATCH * 256), dim3(256), 0, stream,
                       Q2, K2, Vt2, msg0, tki0, tkp0);
    hipLaunchKernelGGL((refine_tm_kernel<32, true>), dim3(BATCH * 256), dim3(256), 0, stream,
                       Qt1, Kt1, Vt1, msg0, tki0, tkp0, msg1, tki1, tkp1);
    hipLaunchKernelGGL((refine_tm_kernel<64, false>), dim3(BATCH * 1024), dim3(256), 0, stream,
                       Qt0, Kt0, Vt0, msg1, tki1, tkp1, out, nullptr, nullptr);
  } else {
    hipLaunchKernelGGL(l0_cm_kernel, dim3(BATCH * 256), dim3(256), 0, stream,
                       Q2, K2, V2, msg0, tki0, tkp0);
    hipLaunchKernelGGL((refine_cm_kernel<32, true>), dim3(BATCH * 256), dim3(256), 0, stream,
                       Q1, K1, V1, msg0, tki0, tkp0, msg1, tki1, tkp1);
    hipLaunchKernelGGL((refine_cm_kernel<64, false>), dim3(BATCH * 1024), dim3(256), 0, stream,
                       Q0, K0, V0, msg1, tki1, tkp1, out, nullptr, nullptr);
  }
}